// Round 19
// baseline (436.012 us; speedup 1.0000x reference)
//
#include <hip/hip_runtime.h>

#define CDIM 384
#define FDIM 1536
#define KK 51
#define RAD 25
#define NPIX 32768     // B*H*W
#define HW 4096        // 64*64

#define CSTR 136       // shifted-copy stride (elements)
#define OSTR 68        // out accumulator row stride (f32 words)

typedef float  f32x4  __attribute__((ext_vector_type(4)));
typedef short  short8 __attribute__((ext_vector_type(8)));
typedef __bf16 bf16x8 __attribute__((ext_vector_type(8)));
typedef unsigned short us4 __attribute__((ext_vector_type(4)));

// per-axis peripheral index: coords {0,1,2,4,8,16,25}, signed list P=13
__device__ __constant__ int AXIS[51] = {
  0,
  1,1,1,1,1,1,1,1,1,
  2,2,2,2,2,2,2,2,
  3,3,3,3,
  4,4,
  5,
  6,
  7,
  8,8,
  9,9,9,9,
  10,10,10,10,10,10,10,10,
  11,11,11,11,11,11,11,11,11,
  12
};

__device__ __forceinline__ unsigned short bf16_rn(float x){
  union { float f; unsigned u; } v; v.f = x;
  unsigned r = v.u + 0x7FFFu + ((v.u >> 16) & 1u);
  return (unsigned short)(r >> 16);
}
__device__ __forceinline__ unsigned short f2bf(float x){
  __bf16 h = (__bf16)x;
  return __builtin_bit_cast(unsigned short, h);
}
__device__ __forceinline__ float bf2f(unsigned short h){
  union { unsigned u; float f; } v; v.u = ((unsigned)h) << 16; return v.f;
}
// fast GELU: v * sigmoid(2*sqrt(2/pi)*(v + 0.044715 v^3)); |err| vs exact erf <= ~1e-3
__device__ __forceinline__ float gelu_f(float v){
  float t = v*(0.7978845608f + 0.0356774081f*v*v);
  float sg = 1.f/(1.f + __expf(-2.f*t));
  return v * sg;
}

// ---------------- K-PREP: one launch for all small prep work.
// blocks [0,384): build wfull   [384,528): w1->w1T   [528,672): w2->w2T
// blocks [672,678): c2 (64 ch each)    [678]: zero grn
__global__ __launch_bounds__(256) void k_prep(const float* __restrict__ wc,
                                              const float* __restrict__ kpe,
                                              float* __restrict__ wfull,
                                              const float* __restrict__ w1,
                                              unsigned short* __restrict__ w1T,
                                              const float* __restrict__ w2,
                                              unsigned short* __restrict__ w2T,
                                              const float* __restrict__ beta,
                                              const float* __restrict__ b2,
                                              float* __restrict__ c2,
                                              float* __restrict__ grn){
  __shared__ float tile[64][65];
  __shared__ float red[256];
  int bid = blockIdx.x;
  int tid = threadIdx.x;
  if (bid < 384){
    int c = bid;
    const float* wcc = wc + c*169;
    float* wo = wfull + (size_t)c*2601;
    for (int idx = tid; idx < 2601; idx += 256){
      int i = idx / 51, j = idx - i*51;
      wo[idx] = wcc[AXIS[i]*13 + AXIS[j]] + kpe[idx];
    }
  } else if (bid < 672){  // transposes
    const float* src; unsigned short* dst; int R, C, t;
    if (bid < 528){ src = w1; dst = w1T; R = CDIM; C = FDIM; t = bid - 384; }
    else          { src = w2; dst = w2T; R = FDIM; C = CDIM; t = bid - 528; }
    int nct = C >> 6;
    int tc = t % nct, tr = t / nct;
    int r0 = tr*64, c0 = tc*64;
    int lane = tid & 63, q = tid >> 6;
    #pragma unroll
    for (int it = 0; it < 16; ++it){
      int r = it*4 + q;
      tile[r][lane] = src[(size_t)(r0 + r)*C + c0 + lane];
    }
    __syncthreads();
    #pragma unroll
    for (int it = 0; it < 16; ++it){
      int c = it*4 + q;
      dst[(size_t)(c0 + c)*R + r0 + lane] = f2bf(tile[lane][c]);
    }
  } else if (bid < 678){
    // c2[c] = b2[c] + sum_f beta[f]*w2[f,c]; lane = channel (coalesced rows)
    int lane = tid & 63, w = tid >> 6;
    int c = (bid - 672)*64 + lane;
    float s = 0.f;
    for (int f = w*384; f < (w + 1)*384; ++f)
      s += beta[f] * w2[(size_t)f*CDIM + c];
    red[w*64 + lane] = s;
    __syncthreads();
    if (tid < 64){
      float t = red[tid] + red[64 + tid] + red[128 + tid] + red[192 + tid];
      c2[c] = t + b2[c];
    }
  } else {
    for (int i = tid; i < 8*FDIM; i += 256) grn[i] = 0.f;
  }
}

// ---------------- K1: depthwise conv 51x51 via MFMA row-Toeplitz scatter,
// 4-row alignment-class batching + async-STAGE split, single-buffered staging.
// Two 1536-block dispatches (img0 offset) for rocprof top-5 visibility.
__global__ __launch_bounds__(256) void k_conv_mfma(const float* __restrict__ x,
                                                   const float* __restrict__ wfull,
                                                   float* __restrict__ y,
                                                   int img0){
  __shared__ __align__(16) float outb[64*OSTR];        // 17408 B accumulator
  __shared__ __align__(16) unsigned short buf[4][1088];// 8704 B row copies (single)
  int img = img0 + blockIdx.x;          // b*384 + c
  int ch  = img % CDIM;
  const float* xim = x + (size_t)img*HW;
  const float* wch = wfull + (size_t)ch*2601;
  int tid = threadIdx.x;
  int lane = tid & 63, wid = tid >> 6;  // wid = q-tile
  int li = lane & 15, g = lane >> 4;
  int t0 = (lane & 31) << 2;            // us4 position within a copy
  int c0 = lane >> 5;                   // base copy index (it adds 2 per step)

  for (int i = tid; i < 1088; i += 256)
    *(f32x4*)&outb[i*4] = (f32x4){0.f,0.f,0.f,0.f};

  bf16x8 Bf[4][2];
  #pragma unroll
  for (int nt = 0; nt < 4; ++nt){
    int i = nt*16 + li;
    #pragma unroll
    for (int kt = 0; kt < 2; ++kt){
      union { bf16x8 v; unsigned short u[8]; } tmp;
      #pragma unroll
      for (int e = 0; e < 8; ++e){
        int j = kt*32 + g*8 + e;
        float v = (i < 51 && j < 51) ? wch[i*51 + j] : 0.f;
        tmp.u[e] = bf16_rn(v);
      }
      Bf[nt][kt] = tmp.v;
    }
  }

  {
    const float* xr = xim + (16*wid)*64;
    #pragma unroll
    for (int it = 0; it < 4; ++it){
      int c = c0 + 2*it;
      us4 o;
      #pragma unroll
      for (int e = 0; e < 4; ++e){
        int xi = t0 + e + c - 25;
        float v = (xi >= 0 && xi < 64) ? xr[xi] : 0.f;
        o[e] = bf16_rn(v);
      }
      *(us4*)&buf[wid][c*CSTR + t0] = o;
    }
  }
  __syncthreads();

  #pragma unroll 1
  for (int ph = 0; ph < 16; ++ph){
    float pf[16];
    if (ph + 1 < 16){
      const float* xr = xim + (ph + 1 + 16*wid)*64;
      #pragma unroll
      for (int it = 0; it < 4; ++it){
        int c = c0 + 2*it;
        #pragma unroll
        for (int e = 0; e < 4; ++e){
          int xi = t0 + e + c - 25;
          int xc = min(max(xi, 0), 63);
          pf[it*4 + e] = xr[xc];
        }
      }
    }

    bf16x8 Af[4][2];
    #pragma unroll
    for (int s = 0; s < 4; ++s){
      const unsigned short* bb = &buf[s][0];
      #pragma unroll
      for (int kt = 0; kt < 2; ++kt){
        int u0 = wid*16 + kt*32 + g*8 + li;
        int c  = li & 7;
        Af[s][kt] = *(const bf16x8*)&bb[c*CSTR + (u0 - c)];
      }
    }

    #pragma unroll
    for (int dd = 0; dd < 6; ++dd){
      int d = dd - 2;
      int pmax = ph + 25 + 16*d;
      if (pmax < 0 || pmax > 78) continue;
      f32x4 V = {0.f,0.f,0.f,0.f};
      #pragma unroll
      for (int s = 0; s < 4; ++s){
        int nt = s - d;
        if (nt < 0 || nt > 3) continue;
        V = __builtin_amdgcn_mfma_f32_16x16x32_bf16(Af[s][0], Bf[nt][0], V, 0, 0, 0);
        V = __builtin_amdgcn_mfma_f32_16x16x32_bf16(Af[s][1], Bf[nt][1], V, 0, 0, 0);
      }
      int p = pmax - li;
      if (p >= 0 && p < 64){
        float* oa = &outb[p*OSTR + wid*16 + g*4];
        f32x4 old = *(const f32x4*)oa;
        *(f32x4*)oa = old + V;
      }
    }

    __syncthreads();
    if (ph + 1 < 16){
      unsigned short* dst = &buf[wid][0];
      #pragma unroll
      for (int it = 0; it < 4; ++it){
        int c = c0 + 2*it;
        us4 o;
        #pragma unroll
        for (int e = 0; e < 4; ++e){
          int xi = t0 + e + c - 25;
          float v = (xi >= 0 && xi < 64) ? pf[it*4 + e] : 0.f;
          o[e] = bf16_rn(v);
        }
        *(us4*)&dst[c*CSTR + t0] = o;
      }
    }
    __syncthreads();
  }

  float* yo = y + (size_t)img*HW;
  #pragma unroll
  for (int k = 0; k < 4; ++k){
    int pix = k*1024 + tid*4;
    int p = pix >> 6, q = pix & 63;
    *(f32x4*)(yo + pix) = *(const f32x4*)&outb[p*OSTR + q];
  }
}

// ---------------- K6: GEMM1, classic 128x128 tiling with FUSED LayerNorm.
// Grid 3072 = 256 pixel-tiles x 12 f-tiles (12 f-tiles of a pixel-tile share an
// XCD -> y slice L2-local). Stats prepass keeps mu/rstd in regs; A staged from
// NCHW y with inline LN (coalesced px loads, 2 aligned b128 LDS writes/thread).
// LDS 45KB -> 3 blocks/CU (old persistent-A: 71.6KB -> 2, occupancy 22%).
__global__ __launch_bounds__(256) void k_gemm1t(const float* __restrict__ y,      // conv out f32 NCHW
                                                const float* __restrict__ lnw,
                                                const float* __restrict__ lnb,
                                                const unsigned short* __restrict__ BT,  // w1T 1536 x 384
                                                const float* __restrict__ b1,
                                                unsigned short* __restrict__ H,         // M x 1536
                                                float* __restrict__ grn){               // 8 x 1536
  __shared__ __align__(16) unsigned short aS[2][128*40];
  __shared__ __align__(16) unsigned short bS[2][128*40];
  __shared__ float sred[2][2][128];
  int bid = blockIdx.x;
  int x8 = bid & 7;
  int kk = bid >> 3;
  int bm = kk % 12;              // f tile
  int bn = x8 + 8*(kk/12);       // pixel tile [0,256)
  int p0 = bn*128, n0 = bm*128;
  int img = p0 >> 12;
  int sp0 = p0 & 4095;
  int tid = threadIdx.x;
  int lane = tid & 63, wid = tid >> 6;
  int wr = wid >> 1, wc = wid & 1;
  int lm = lane & 15, g = lane >> 4;
  int px = tid & 127, hh = tid >> 7;   // stats + A-staging role
  int sr = tid & 127, sc = tid >> 7;   // B staging role

  // ---- LN stats: thread sums 192 channels of its pixel (coalesced along px)
  const float* yb = y + (size_t)img*CDIM*HW + sp0 + px;
  {
    float sum = 0.f, sq = 0.f;
    for (int c = hh*192; c < hh*192 + 192; ++c){
      float v = yb[(size_t)c*HW];
      sum += v; sq += v*v;
    }
    sred[hh][0][px] = sum; sred[hh][1][px] = sq;
  }
  __syncthreads();
  float mu, rstd;
  {
    float ts = sred[0][0][px] + sred[1][0][px];
    float tq = sred[0][1][px] + sred[1][1][px];
    mu   = ts * (1.f/CDIM);
    rstd = rsqrtf(tq * (1.f/CDIM) - mu*mu + 1e-6f);
  }

  // prologue: step0 -> buf0; prefetch step1 -> regs
  {
    short8 o0, o1;
    #pragma unroll
    for (int e = 0; e < 8; ++e){
      int c = hh*16 + e;
      o0[e] = (short)f2bf((yb[(size_t)c*HW] - mu)*rstd*lnw[c] + lnb[c]);
      int c2_ = hh*16 + 8 + e;
      o1[e] = (short)f2bf((yb[(size_t)c2_*HW] - mu)*rstd*lnw[c2_] + lnb[c2_]);
    }
    *(short8*)&aS[0][px*40 + hh*16]     = o0;
    *(short8*)&aS[0][px*40 + hh*16 + 8] = o1;
    const unsigned short* gb = BT + (size_t)(n0 + sr)*CDIM + sc*16;
    *(short8*)&bS[0][sr*40 + sc*16]     = *(const short8*)(gb);
    *(short8*)&bS[0][sr*40 + sc*16 + 8] = *(const short8*)(gb + 8);
  }
  float apre[16];
  short8 bpre0, bpre1;
  {
    #pragma unroll
    for (int e = 0; e < 16; ++e) apre[e] = yb[(size_t)(32 + hh*16 + e)*HW];
    const unsigned short* gb = BT + (size_t)(n0 + sr)*CDIM + 32 + sc*16;
    bpre0 = *(const short8*)(gb); bpre1 = *(const short8*)(gb + 8);
  }
  int par = 0;
  f32x4 acc[4][4];
  #pragma unroll
  for (int i = 0; i < 4; ++i)
    #pragma unroll
    for (int j = 0; j < 4; ++j) acc[i][j] = (f32x4){0.f,0.f,0.f,0.f};

  #pragma unroll 1
  for (int ks = 0; ks < 12; ++ks){
    __syncthreads();
    if (ks + 1 < 12){
      int ck = (ks + 1)*32 + hh*16;
      short8 o0, o1;
      #pragma unroll
      for (int e = 0; e < 8; ++e){
        o0[e] = (short)f2bf((apre[e]     - mu)*rstd*lnw[ck + e]     + lnb[ck + e]);
        o1[e] = (short)f2bf((apre[8 + e] - mu)*rstd*lnw[ck + 8 + e] + lnb[ck + 8 + e]);
      }
      *(short8*)&aS[par^1][px*40 + hh*16]     = o0;
      *(short8*)&aS[par^1][px*40 + hh*16 + 8] = o1;
      *(short8*)&bS[par^1][sr*40 + sc*16]     = bpre0;
      *(short8*)&bS[par^1][sr*40 + sc*16 + 8] = bpre1;
    }
    if (ks + 2 < 12){
      int ck = (ks + 2)*32;
      #pragma unroll
      for (int e = 0; e < 16; ++e) apre[e] = yb[(size_t)(ck + hh*16 + e)*HW];
      const unsigned short* gb = BT + (size_t)(n0 + sr)*CDIM + ck + sc*16;
      bpre0 = *(const short8*)(gb); bpre1 = *(const short8*)(gb + 8);
    }
    bf16x8 aF[4], bF[4];
    #pragma unroll
    for (int fm = 0; fm < 4; ++fm) aF[fm] = *(const bf16x8*)&aS[par][(wr*64 + fm*16 + lm)*40 + g*8];
    #pragma unroll
    for (int fn = 0; fn < 4; ++fn) bF[fn] = *(const bf16x8*)&bS[par][(wc*64 + fn*16 + lm)*40 + g*8];
    #pragma unroll
    for (int fm = 0; fm < 4; ++fm)
      #pragma unroll
      for (int fn = 0; fn < 4; ++fn)
        acc[fm][fn] = __builtin_amdgcn_mfma_f32_16x16x32_bf16(aF[fm], bF[fn], acc[fm][fn], 0, 0, 0);
    par ^= 1;
  }

  // epilogue: bias + GELU -> H bf16; GRN partial sums
  float psum[4] = {0.f,0.f,0.f,0.f};
  #pragma unroll
  for (int fn = 0; fn < 4; ++fn){
    int n = n0 + wc*64 + fn*16 + lm;
    float bias = b1[n];
    #pragma unroll
    for (int fm = 0; fm < 4; ++fm){
      int mb = p0 + wr*64 + fm*16 + g*4;
      #pragma unroll
      for (int r = 0; r < 4; ++r){
        float v = gelu_f(acc[fm][fn][r] + bias);
        H[(size_t)(mb + r)*FDIM + n] = f2bf(v);
        psum[fn] += v*v;
      }
    }
  }
  #pragma unroll
  for (int fn = 0; fn < 4; ++fn){
    float v = psum[fn];
    v += __shfl_xor(v, 16);
    v += __shfl_xor(v, 32);
    if (g == 0){
      atomicAdd(&grn[img*FDIM + n0 + wc*64 + fn*16 + lm], v);
    }
  }
}

// ---------------- K7: GRN finalize -> S[n,f] = 1 + gamma[f]*nx
__global__ __launch_bounds__(256) void k_grn(const float* __restrict__ grn,
                                             const float* __restrict__ gamma,
                                             float* __restrict__ S){
  int n = blockIdx.x;
  const float* g = grn + n*FDIM;
  __shared__ float red[256];
  float p = 0.f;
  for (int f = threadIdx.x; f < FDIM; f += 256) p += sqrtf(g[f]);
  red[threadIdx.x] = p;
  __syncthreads();
  for (int s = 128; s > 0; s >>= 1){
    if (threadIdx.x < s) red[threadIdx.x] += red[threadIdx.x + s];
    __syncthreads();
  }
  float mean = red[0] * (1.f/FDIM);
  float inv = 1.f/(mean + 1e-6f);
  for (int f = threadIdx.x; f < FDIM; f += 256){
    float nx = sqrtf(g[f]) * inv;
    S[n*FDIM + f] = 1.f + gamma[f]*nx;
  }
}

// ---------------- K-SCALE: W2s[img][c][f] = bf16( w2T[c][f] * S[img][f] )
__global__ __launch_bounds__(256) void k_scale(const unsigned short* __restrict__ w2T,
                                               const float* __restrict__ S,
                                               unsigned short* __restrict__ W2s){
  int img = blockIdx.y;
  size_t base = ((size_t)blockIdx.x*256 + threadIdx.x)*8;   // < 384*1536
  int f0 = (int)(base % FDIM);                              // 8 | FDIM -> f contiguous
  const float* Si = S + img*FDIM + f0;
  short8 wv = *(const short8*)(w2T + base);
  short8 o;
  #pragma unroll
  for (int e = 0; e < 8; ++e)
    o[e] = (short)f2bf(bf2f((unsigned short)wv[e]) * Si[e]);
  *(short8*)(W2s + (size_t)img*CDIM*FDIM + base) = o;
}

// ---------------- K9: GEMM2, single-barrier dbuf, pure-copy staging (S pre-folded).
__global__ __launch_bounds__(256) void k_gemm2(const unsigned short* __restrict__ W2s, // [8][384][1536]
                                               const unsigned short* __restrict__ H,   // M x 1536
                                               const float* __restrict__ c2,
                                               const float* __restrict__ xg,
                                               float* __restrict__ out){
  __shared__ __align__(16) unsigned short aS[2][128*40];
  __shared__ __align__(16) unsigned short bS[2][128*40];
  int bid = blockIdx.x;
  int x8 = bid & 7;            // XCD id
  int kk = bid >> 3;
  int bm = kk % 3;             // channel tile
  int bn = x8 + 8*(kk / 3);    // pixel tile
  int c0 = bm*128, p0 = bn*128;
  int img = p0 >> 12;
  const unsigned short* Wimg = W2s + (size_t)img*CDIM*FDIM;
  int tid = threadIdx.x;
  int lane = tid & 63, wid = tid >> 6;
  int wr = wid >> 1, wc = wid & 1;
  int lm = lane & 15, g = lane >> 4;
  int sr = tid & 127, sc = tid >> 7;
  f32x4 acc[4][4];
  #pragma unroll
  for (int i = 0; i < 4; ++i)
    #pragma unroll
    for (int j = 0; j < 4; ++j) acc[i][j] = (f32x4){0.f,0.f,0.f,0.f};

  // prologue: step0 directly to LDS; step1 to regs
  {
    const unsigned short* ga = Wimg + (size_t)(c0 + sr)*FDIM + sc*16;
    *(short8*)&aS[0][sr*40 + sc*16]     = *(const short8*)(ga);
    *(short8*)&aS[0][sr*40 + sc*16 + 8] = *(const short8*)(ga + 8);
    const unsigned short* gb = H + (size_t)(p0 + sr)*FDIM + sc*16;
    *(short8*)&bS[0][sr*40 + sc*16]     = *(const short8*)(gb);
    *(short8*)&bS[0][sr*40 + sc*16 + 8] = *(const short8*)(gb + 8);
  }
  short8 ra0, ra1, rh0, rh1;
  {
    const unsigned short* ga = Wimg + (size_t)(c0 + sr)*FDIM + 32 + sc*16;
    ra0 = *(const short8*)(ga); ra1 = *(const short8*)(ga + 8);
    const unsigned short* gb = H + (size_t)(p0 + sr)*FDIM + 32 + sc*16;
    rh0 = *(const short8*)(gb); rh1 = *(const short8*)(gb + 8);
  }
  int par = 0;

  #pragma unroll 1
  for (int ks = 0; ks < 48; ++ks){
    __syncthreads();
    if (ks + 1 < 48){
      *(short8*)&aS[par^1][sr*40 + sc*16]     = ra0;
      *(short8*)&aS[par^1][sr*40 + sc*16 + 8] = ra1;
      *(short8*)&bS[par^1][sr*40 + sc*16]     = rh0;
      *(short8*)&bS[par^1][sr*40 + sc*16 + 8] = rh1;
    }
    if (ks + 2 < 48){
      int nk = (ks + 2)*32;
      const unsigned short* ga = Wimg + (size_t)(c0 + sr)*FDIM + nk + sc*16;
      ra0 = *(const short8*)(ga); ra1 = *(const short8*)(ga + 8);
      const unsigned short* gb = H + (size_t)(p0 + sr)*FDIM + nk + sc*16;
      rh0 = *(const short8*)(gb); rh1 = *(const short8*)(gb + 8);
    }
    bf16x8 aF[4], bF[4];
    #pragma unroll
    for (int fm = 0; fm < 4; ++fm) aF[fm] = *(const bf16x8*)&aS[par][(wr*64 + fm*16 + lm)*40 + g*8];
    #pragma unroll
    for (int fn = 0; fn < 4; ++fn) bF[fn] = *(const bf16x8*)&bS[par][(wc*64 + fn*16 + lm)*40 + g*8];
    #pragma unroll
    for (int fm = 0; fm < 4; ++fm)
      #pragma unroll
      for (int fn = 0; fn < 4; ++fn)
        acc[fm][fn] = __builtin_amdgcn_mfma_f32_16x16x32_bf16(aF[fm], bF[fn], acc[fm][fn], 0, 0, 0);
    par ^= 1;
  }

  int sp0 = p0 & 4095;
  #pragma unroll
  for (int fn = 0; fn < 4; ++fn){
    int pixoff = sp0 + wc*64 + fn*16 + lm;
    #pragma unroll
    for (int fm = 0; fm < 4; ++fm){
      #pragma unroll
      for (int r = 0; r < 4; ++r){
        int c = c0 + wr*64 + fm*16 + g*4 + r;
        size_t addr = ((size_t)img*CDIM + c)*HW + pixoff;
        out[addr] = acc[fm][fn][r] + c2[c] + xg[addr];
      }
    }
  }
}

extern "C" void kernel_launch(void* const* d_in, const int* in_sizes, int n_in,
                              void* d_out, int out_size, void* d_ws, size_t ws_size,
                              hipStream_t stream) {
  const float* x    = (const float*)d_in[0];
  const float* wc   = (const float*)d_in[1];
  const float* kpe  = (const float*)d_in[2];
  const float* lnw  = (const float*)d_in[3];
  const float* lnb  = (const float*)d_in[4];
  const float* w1   = (const float*)d_in[5];
  const float* b1   = (const float*)d_in[6];
  const float* gam  = (const float*)d_in[7];
  const float* beta = (const float*)d_in[8];
  const float* w2   = (const float*)d_in[9];
  const float* b2   = (const float*)d_in[10];
  float* out = (float*)d_out;

  char* ws = (char*)d_ws;
  size_t o = 0;
  auto take = [&](size_t bytes)->char*{
    char* p = ws + o;
    o = (o + bytes + 511) & ~(size_t)511;
    return p;
  };
  // y (conv output) aliases d_out: fully consumed by k_gemm1t (fused LN) before
  // k_gemm2 writes the real output.
  float*          y     = out;
  float*          wfull = (float*)take((size_t)CDIM*2601*4);
  unsigned short* H     = (unsigned short*)take((size_t)NPIX*FDIM*2);
  unsigned short* w1T   = (unsigned short*)take((size_t)CDIM*FDIM*2);
  unsigned short* w2T   = (unsigned short*)take((size_t)CDIM*FDIM*2);
  unsigned short* W2s   = (unsigned short*)take((size_t)8*CDIM*FDIM*2);
  float*          grn   = (float*)take(8*FDIM*4);
  float*          S     = (float*)take(8*FDIM*4);
  float*          c2    = (float*)take(CDIM*4);
  if (o > ws_size) return;

  k_prep<<<679, 256, 0, stream>>>(wc, kpe, wfull, w1, w1T, w2, w2T, beta, b2, c2, grn);
  k_conv_mfma<<<1536, 256, 0, stream>>>(x, wfull, y, 0);
  k_conv_mfma<<<1536, 256, 0, stream>>>(x, wfull, y, 1536);
  k_gemm1t<<<3072, 256, 0, stream>>>(y, lnw, lnb, w1T, b1, H, grn);
  k_grn<<<8, 256, 0, stream>>>(grn, gam, S);
  k_scale<<<dim3(288, 8), 256, 0, stream>>>(w2T, S, W2s);
  k_gemm2<<<3*(NPIX/128), 256, 0, stream>>>(W2s, H, c2, x, out);
}

// Round 20
// 428.937 us; speedup vs baseline: 1.0165x; 1.0165x over previous
//
#include <hip/hip_runtime.h>

#define CDIM 384
#define FDIM 1536
#define KK 51
#define RAD 25
#define NPIX 32768     // B*H*W
#define HW 4096        // 64*64

#define CSTR 136       // shifted-copy stride (elements)
#define OSTR 68        // out accumulator row stride (f32 words)

typedef float  f32x4  __attribute__((ext_vector_type(4)));
typedef short  short8 __attribute__((ext_vector_type(8)));
typedef __bf16 bf16x8 __attribute__((ext_vector_type(8)));
typedef unsigned short us4 __attribute__((ext_vector_type(4)));

// per-axis peripheral index: coords {0,1,2,4,8,16,25}, signed list P=13
__device__ __constant__ int AXIS[51] = {
  0,
  1,1,1,1,1,1,1,1,1,
  2,2,2,2,2,2,2,2,
  3,3,3,3,
  4,4,
  5,
  6,
  7,
  8,8,
  9,9,9,9,
  10,10,10,10,10,10,10,10,
  11,11,11,11,11,11,11,11,11,
  12
};

__device__ __forceinline__ unsigned short bf16_rn(float x){
  union { float f; unsigned u; } v; v.f = x;
  unsigned r = v.u + 0x7FFFu + ((v.u >> 16) & 1u);
  return (unsigned short)(r >> 16);
}
__device__ __forceinline__ unsigned short f2bf(float x){
  __bf16 h = (__bf16)x;
  return __builtin_bit_cast(unsigned short, h);
}
__device__ __forceinline__ float bf2f(unsigned short h){
  union { unsigned u; float f; } v; v.u = ((unsigned)h) << 16; return v.f;
}
// fast GELU: v * sigmoid(2*sqrt(2/pi)*(v + 0.044715 v^3)); |err| vs exact erf <= ~1e-3
__device__ __forceinline__ float gelu_f(float v){
  float t = v*(0.7978845608f + 0.0356774081f*v*v);
  float sg = 1.f/(1.f + __expf(-2.f*t));
  return v * sg;
}

// ---------------- K-PREP: one launch for all small prep work.
// blocks [0,384): build wfull   [384,528): w1->w1T   [528,672): w2->w2T
// blocks [672,678): c2 (64 ch each)    [678]: zero grn
__global__ __launch_bounds__(256) void k_prep(const float* __restrict__ wc,
                                              const float* __restrict__ kpe,
                                              float* __restrict__ wfull,
                                              const float* __restrict__ w1,
                                              unsigned short* __restrict__ w1T,
                                              const float* __restrict__ w2,
                                              unsigned short* __restrict__ w2T,
                                              const float* __restrict__ beta,
                                              const float* __restrict__ b2,
                                              float* __restrict__ c2,
                                              float* __restrict__ grn){
  __shared__ float tile[64][65];
  __shared__ float red[256];
  int bid = blockIdx.x;
  int tid = threadIdx.x;
  if (bid < 384){
    int c = bid;
    const float* wcc = wc + c*169;
    float* wo = wfull + (size_t)c*2601;
    for (int idx = tid; idx < 2601; idx += 256){
      int i = idx / 51, j = idx - i*51;
      wo[idx] = wcc[AXIS[i]*13 + AXIS[j]] + kpe[idx];
    }
  } else if (bid < 672){  // transposes
    const float* src; unsigned short* dst; int R, C, t;
    if (bid < 528){ src = w1; dst = w1T; R = CDIM; C = FDIM; t = bid - 384; }
    else          { src = w2; dst = w2T; R = FDIM; C = CDIM; t = bid - 528; }
    int nct = C >> 6;
    int tc = t % nct, tr = t / nct;
    int r0 = tr*64, c0 = tc*64;
    int lane = tid & 63, q = tid >> 6;
    #pragma unroll
    for (int it = 0; it < 16; ++it){
      int r = it*4 + q;
      tile[r][lane] = src[(size_t)(r0 + r)*C + c0 + lane];
    }
    __syncthreads();
    #pragma unroll
    for (int it = 0; it < 16; ++it){
      int c = it*4 + q;
      dst[(size_t)(c0 + c)*R + r0 + lane] = f2bf(tile[lane][c]);
    }
  } else if (bid < 678){
    // c2[c] = b2[c] + sum_f beta[f]*w2[f,c]; lane = channel (coalesced rows)
    int lane = tid & 63, w = tid >> 6;
    int c = (bid - 672)*64 + lane;
    float s = 0.f;
    for (int f = w*384; f < (w + 1)*384; ++f)
      s += beta[f] * w2[(size_t)f*CDIM + c];
    red[w*64 + lane] = s;
    __syncthreads();
    if (tid < 64){
      float t = red[tid] + red[64 + tid] + red[128 + tid] + red[192 + tid];
      c2[c] = t + b2[c];
    }
  } else {
    for (int i = tid; i < 8*FDIM; i += 256) grn[i] = 0.f;
  }
}

// ---------------- K1: depthwise conv 51x51 via MFMA row-Toeplitz scatter,
// 4-row alignment-class batching + async-STAGE split, single-buffered staging.
// Two 1536-block dispatches (img0 offset) for rocprof top-5 visibility.
__global__ __launch_bounds__(256) void k_conv_mfma(const float* __restrict__ x,
                                                   const float* __restrict__ wfull,
                                                   float* __restrict__ y,
                                                   int img0){
  __shared__ __align__(16) float outb[64*OSTR];        // 17408 B accumulator
  __shared__ __align__(16) unsigned short buf[4][1088];// 8704 B row copies (single)
  int img = img0 + blockIdx.x;          // b*384 + c
  int ch  = img % CDIM;
  const float* xim = x + (size_t)img*HW;
  const float* wch = wfull + (size_t)ch*2601;
  int tid = threadIdx.x;
  int lane = tid & 63, wid = tid >> 6;  // wid = q-tile
  int li = lane & 15, g = lane >> 4;
  int t0 = (lane & 31) << 2;            // us4 position within a copy
  int c0 = lane >> 5;                   // base copy index (it adds 2 per step)

  for (int i = tid; i < 1088; i += 256)
    *(f32x4*)&outb[i*4] = (f32x4){0.f,0.f,0.f,0.f};

  bf16x8 Bf[4][2];
  #pragma unroll
  for (int nt = 0; nt < 4; ++nt){
    int i = nt*16 + li;
    #pragma unroll
    for (int kt = 0; kt < 2; ++kt){
      union { bf16x8 v; unsigned short u[8]; } tmp;
      #pragma unroll
      for (int e = 0; e < 8; ++e){
        int j = kt*32 + g*8 + e;
        float v = (i < 51 && j < 51) ? wch[i*51 + j] : 0.f;
        tmp.u[e] = bf16_rn(v);
      }
      Bf[nt][kt] = tmp.v;
    }
  }

  {
    const float* xr = xim + (16*wid)*64;
    #pragma unroll
    for (int it = 0; it < 4; ++it){
      int c = c0 + 2*it;
      us4 o;
      #pragma unroll
      for (int e = 0; e < 4; ++e){
        int xi = t0 + e + c - 25;
        float v = (xi >= 0 && xi < 64) ? xr[xi] : 0.f;
        o[e] = bf16_rn(v);
      }
      *(us4*)&buf[wid][c*CSTR + t0] = o;
    }
  }
  __syncthreads();

  #pragma unroll 1
  for (int ph = 0; ph < 16; ++ph){
    float pf[16];
    if (ph + 1 < 16){
      const float* xr = xim + (ph + 1 + 16*wid)*64;
      #pragma unroll
      for (int it = 0; it < 4; ++it){
        int c = c0 + 2*it;
        #pragma unroll
        for (int e = 0; e < 4; ++e){
          int xi = t0 + e + c - 25;
          int xc = min(max(xi, 0), 63);
          pf[it*4 + e] = xr[xc];
        }
      }
    }

    bf16x8 Af[4][2];
    #pragma unroll
    for (int s = 0; s < 4; ++s){
      const unsigned short* bb = &buf[s][0];
      #pragma unroll
      for (int kt = 0; kt < 2; ++kt){
        int u0 = wid*16 + kt*32 + g*8 + li;
        int c  = li & 7;
        Af[s][kt] = *(const bf16x8*)&bb[c*CSTR + (u0 - c)];
      }
    }

    #pragma unroll
    for (int dd = 0; dd < 6; ++dd){
      int d = dd - 2;
      int pmax = ph + 25 + 16*d;
      if (pmax < 0 || pmax > 78) continue;
      f32x4 V = {0.f,0.f,0.f,0.f};
      #pragma unroll
      for (int s = 0; s < 4; ++s){
        int nt = s - d;
        if (nt < 0 || nt > 3) continue;
        V = __builtin_amdgcn_mfma_f32_16x16x32_bf16(Af[s][0], Bf[nt][0], V, 0, 0, 0);
        V = __builtin_amdgcn_mfma_f32_16x16x32_bf16(Af[s][1], Bf[nt][1], V, 0, 0, 0);
      }
      int p = pmax - li;
      if (p >= 0 && p < 64){
        float* oa = &outb[p*OSTR + wid*16 + g*4];
        f32x4 old = *(const f32x4*)oa;
        *(f32x4*)oa = old + V;
      }
    }

    __syncthreads();
    if (ph + 1 < 16){
      unsigned short* dst = &buf[wid][0];
      #pragma unroll
      for (int it = 0; it < 4; ++it){
        int c = c0 + 2*it;
        us4 o;
        #pragma unroll
        for (int e = 0; e < 4; ++e){
          int xi = t0 + e + c - 25;
          float v = (xi >= 0 && xi < 64) ? pf[it*4 + e] : 0.f;
          o[e] = bf16_rn(v);
        }
        *(us4*)&dst[c*CSTR + t0] = o;
      }
    }
    __syncthreads();
  }

  float* yo = y + (size_t)img*HW;
  #pragma unroll
  for (int k = 0; k < 4; ++k){
    int pix = k*1024 + tid*4;
    int p = pix >> 6, q = pix & 63;
    *(f32x4*)(yo + pix) = *(const f32x4*)&outb[p*OSTR + q];
  }
}

// ---------------- K6: GEMM1 with FUSED LayerNorm, BARRIER-FREE k-loop:
// A panel (64px x 384) in LDS (read-only after one barrier); B fragments
// streamed per-lane straight from global w1T (1.125 MB, L2-resident; row base
// is k-independent -> pointer walk, 64B/step, sequential per lane). No LDS
// B-staging, no k-loop barriers -> waves independent, deep pipelining.
__global__ __launch_bounds__(256) void k_gemm1g(const float* __restrict__ y,      // conv out f32 NCHW
                                                const float* __restrict__ lnw,
                                                const float* __restrict__ lnb,
                                                const unsigned short* __restrict__ BT,  // w1T 1536 x 384
                                                const float* __restrict__ b1,
                                                unsigned short* __restrict__ H,         // M x 1536
                                                float* __restrict__ grn){               // 8 x 1536
  __shared__ __align__(16) unsigned short pan[64*392];     // 49.1 KB A panel
  __shared__ float sred[2][4][64];
  int m0 = blockIdx.x * 64;
  int img = m0 >> 12;
  int tid = threadIdx.x;
  int lane = tid & 63, wid = tid >> 6;
  int wr = wid >> 1, wc = wid & 1;     // wave tile: 32 pixels x 64 f
  int lm = lane & 15, g = lane >> 4;

  // ---- fused LN: lane = pixel (64 per block), wave = channel quarter [96w, 96w+96)
  {
    int sp0 = m0 & 4095;
    const float* yb = y + (size_t)img*CDIM*HW + sp0 + lane;
    int cbase = wid*96;
    float v[96];
    float sum = 0.f, sq = 0.f;
    #pragma unroll
    for (int cc = 0; cc < 96; ++cc){
      float t = yb[(size_t)(cbase + cc)*HW];
      v[cc] = t; sum += t; sq += t*t;
    }
    sred[0][wid][lane] = sum; sred[1][wid][lane] = sq;
    __syncthreads();
    float ts = 0.f, tq = 0.f;
    #pragma unroll
    for (int u = 0; u < 4; ++u){ ts += sred[0][u][lane]; tq += sred[1][u][lane]; }
    float mu   = ts * (1.f/CDIM);
    float rstd = rsqrtf(tq * (1.f/CDIM) - mu*mu + 1e-6f);
    #pragma unroll
    for (int j = 0; j < 12; ++j){
      short8 o;
      #pragma unroll
      for (int e = 0; e < 8; ++e){
        int c = cbase + j*8 + e;
        float t = (v[j*8 + e] - mu) * rstd * lnw[c] + lnb[c];
        o[e] = (short)f2bf(t);
      }
      *(short8*)&pan[lane*392 + cbase + j*8] = o;   // row = pixel, contiguous c
    }
  }
  __syncthreads();   // pan ready; ONLY barrier in the kernel body

  // per-lane B row bases (k-independent): row = n0 + wc*64 + fn*16 + lm
  const unsigned short* brow[4];
  #pragma unroll
  for (int fn = 0; fn < 4; ++fn)
    brow[fn] = BT + (size_t)(wc*64 + fn*16 + lm)*CDIM + g*8;

  #pragma unroll 1
  for (int ft = 0; ft < 12; ++ft){
    int n0 = ft*128;
    const unsigned short* bp[4];
    #pragma unroll
    for (int fn = 0; fn < 4; ++fn) bp[fn] = brow[fn] + (size_t)n0*CDIM;

    f32x4 acc[2][4];
    #pragma unroll
    for (int i = 0; i < 2; ++i)
      #pragma unroll
      for (int j = 0; j < 4; ++j) acc[i][j] = (f32x4){0.f,0.f,0.f,0.f};

    bf16x8 bcur[4];
    #pragma unroll
    for (int fn = 0; fn < 4; ++fn) bcur[fn] = *(const bf16x8*)(bp[fn]);

    #pragma unroll 1
    for (int ks = 0; ks < 12; ++ks){
      int k0 = ks*32;
      bf16x8 bnext[4];
      if (ks + 1 < 12){
        #pragma unroll
        for (int fn = 0; fn < 4; ++fn) bnext[fn] = *(const bf16x8*)(bp[fn] + (ks + 1)*32);
      }
      bf16x8 aF[2];
      #pragma unroll
      for (int fm = 0; fm < 2; ++fm) aF[fm] = *(const bf16x8*)&pan[(wr*32 + fm*16 + lm)*392 + k0 + g*8];
      #pragma unroll
      for (int fm = 0; fm < 2; ++fm)
        #pragma unroll
        for (int fn = 0; fn < 4; ++fn)
          acc[fm][fn] = __builtin_amdgcn_mfma_f32_16x16x32_bf16(aF[fm], bcur[fn], acc[fm][fn], 0, 0, 0);
      #pragma unroll
      for (int fn = 0; fn < 4; ++fn) bcur[fn] = bnext[fn];
    }

    float psum[4] = {0.f,0.f,0.f,0.f};
    #pragma unroll
    for (int fn = 0; fn < 4; ++fn){
      int n = n0 + wc*64 + fn*16 + lm;
      float bias = b1[n];
      #pragma unroll
      for (int fm = 0; fm < 2; ++fm){
        int mb = m0 + wr*32 + fm*16 + g*4;
        #pragma unroll
        for (int r = 0; r < 4; ++r){
          float v = gelu_f(acc[fm][fn][r] + bias);
          H[(size_t)(mb + r)*FDIM + n] = f2bf(v);
          psum[fn] += v*v;
        }
      }
    }
    #pragma unroll
    for (int fn = 0; fn < 4; ++fn){
      float v = psum[fn];
      v += __shfl_xor(v, 16);
      v += __shfl_xor(v, 32);
      if (g == 0){
        atomicAdd(&grn[img*FDIM + n0 + wc*64 + fn*16 + lm], v);
      }
    }
  }
}

// ---------------- K7: GRN finalize -> S[n,f] = 1 + gamma[f]*nx
__global__ __launch_bounds__(256) void k_grn(const float* __restrict__ grn,
                                             const float* __restrict__ gamma,
                                             float* __restrict__ S){
  int n = blockIdx.x;
  const float* g = grn + n*FDIM;
  __shared__ float red[256];
  float p = 0.f;
  for (int f = threadIdx.x; f < FDIM; f += 256) p += sqrtf(g[f]);
  red[threadIdx.x] = p;
  __syncthreads();
  for (int s = 128; s > 0; s >>= 1){
    if (threadIdx.x < s) red[threadIdx.x] += red[threadIdx.x + s];
    __syncthreads();
  }
  float mean = red[0] * (1.f/FDIM);
  float inv = 1.f/(mean + 1e-6f);
  for (int f = threadIdx.x; f < FDIM; f += 256){
    float nx = sqrtf(g[f]) * inv;
    S[n*FDIM + f] = 1.f + gamma[f]*nx;
  }
}

// ---------------- K-SCALE: W2s[img][c][f] = bf16( w2T[c][f] * S[img][f] )
__global__ __launch_bounds__(256) void k_scale(const unsigned short* __restrict__ w2T,
                                               const float* __restrict__ S,
                                               unsigned short* __restrict__ W2s){
  int img = blockIdx.y;
  size_t base = ((size_t)blockIdx.x*256 + threadIdx.x)*8;   // < 384*1536
  int f0 = (int)(base % FDIM);                              // 8 | FDIM -> f contiguous
  const float* Si = S + img*FDIM + f0;
  short8 wv = *(const short8*)(w2T + base);
  short8 o;
  #pragma unroll
  for (int e = 0; e < 8; ++e)
    o[e] = (short)f2bf(bf2f((unsigned short)wv[e]) * Si[e]);
  *(short8*)(W2s + (size_t)img*CDIM*FDIM + base) = o;
}

// ---------------- K9: GEMM2, single-barrier dbuf, pure-copy staging (S pre-folded).
__global__ __launch_bounds__(256) void k_gemm2(const unsigned short* __restrict__ W2s, // [8][384][1536]
                                               const unsigned short* __restrict__ H,   // M x 1536
                                               const float* __restrict__ c2,
                                               const float* __restrict__ xg,
                                               float* __restrict__ out){
  __shared__ __align__(16) unsigned short aS[2][128*40];
  __shared__ __align__(16) unsigned short bS[2][128*40];
  int bid = blockIdx.x;
  int x8 = bid & 7;            // XCD id
  int kk = bid >> 3;
  int bm = kk % 3;             // channel tile
  int bn = x8 + 8*(kk / 3);    // pixel tile
  int c0 = bm*128, p0 = bn*128;
  int img = p0 >> 12;
  const unsigned short* Wimg = W2s + (size_t)img*CDIM*FDIM;
  int tid = threadIdx.x;
  int lane = tid & 63, wid = tid >> 6;
  int wr = wid >> 1, wc = wid & 1;
  int lm = lane & 15, g = lane >> 4;
  int sr = tid & 127, sc = tid >> 7;
  f32x4 acc[4][4];
  #pragma unroll
  for (int i = 0; i < 4; ++i)
    #pragma unroll
    for (int j = 0; j < 4; ++j) acc[i][j] = (f32x4){0.f,0.f,0.f,0.f};

  // prologue: step0 directly to LDS; step1 to regs
  {
    const unsigned short* ga = Wimg + (size_t)(c0 + sr)*FDIM + sc*16;
    *(short8*)&aS[0][sr*40 + sc*16]     = *(const short8*)(ga);
    *(short8*)&aS[0][sr*40 + sc*16 + 8] = *(const short8*)(ga + 8);
    const unsigned short* gb = H + (size_t)(p0 + sr)*FDIM + sc*16;
    *(short8*)&bS[0][sr*40 + sc*16]     = *(const short8*)(gb);
    *(short8*)&bS[0][sr*40 + sc*16 + 8] = *(const short8*)(gb + 8);
  }
  short8 ra0, ra1, rh0, rh1;
  {
    const unsigned short* ga = Wimg + (size_t)(c0 + sr)*FDIM + 32 + sc*16;
    ra0 = *(const short8*)(ga); ra1 = *(const short8*)(ga + 8);
    const unsigned short* gb = H + (size_t)(p0 + sr)*FDIM + 32 + sc*16;
    rh0 = *(const short8*)(gb); rh1 = *(const short8*)(gb + 8);
  }
  int par = 0;

  #pragma unroll 1
  for (int ks = 0; ks < 48; ++ks){
    __syncthreads();
    if (ks + 1 < 48){
      *(short8*)&aS[par^1][sr*40 + sc*16]     = ra0;
      *(short8*)&aS[par^1][sr*40 + sc*16 + 8] = ra1;
      *(short8*)&bS[par^1][sr*40 + sc*16]     = rh0;
      *(short8*)&bS[par^1][sr*40 + sc*16 + 8] = rh1;
    }
    if (ks + 2 < 48){
      int nk = (ks + 2)*32;
      const unsigned short* ga = Wimg + (size_t)(c0 + sr)*FDIM + nk + sc*16;
      ra0 = *(const short8*)(ga); ra1 = *(const short8*)(ga + 8);
      const unsigned short* gb = H + (size_t)(p0 + sr)*FDIM + nk + sc*16;
      rh0 = *(const short8*)(gb); rh1 = *(const short8*)(gb + 8);
    }
    bf16x8 aF[4], bF[4];
    #pragma unroll
    for (int fm = 0; fm < 4; ++fm) aF[fm] = *(const bf16x8*)&aS[par][(wr*64 + fm*16 + lm)*40 + g*8];
    #pragma unroll
    for (int fn = 0; fn < 4; ++fn) bF[fn] = *(const bf16x8*)&bS[par][(wc*64 + fn*16 + lm)*40 + g*8];
    #pragma unroll
    for (int fm = 0; fm < 4; ++fm)
      #pragma unroll
      for (int fn = 0; fn < 4; ++fn)
        acc[fm][fn] = __builtin_amdgcn_mfma_f32_16x16x32_bf16(aF[fm], bF[fn], acc[fm][fn], 0, 0, 0);
    par ^= 1;
  }

  int sp0 = p0 & 4095;
  #pragma unroll
  for (int fn = 0; fn < 4; ++fn){
    int pixoff = sp0 + wc*64 + fn*16 + lm;
    #pragma unroll
    for (int fm = 0; fm < 4; ++fm){
      #pragma unroll
      for (int r = 0; r < 4; ++r){
        int c = c0 + wr*64 + fm*16 + g*4 + r;
        size_t addr = ((size_t)img*CDIM + c)*HW + pixoff;
        out[addr] = acc[fm][fn][r] + c2[c] + xg[addr];
      }
    }
  }
}

extern "C" void kernel_launch(void* const* d_in, const int* in_sizes, int n_in,
                              void* d_out, int out_size, void* d_ws, size_t ws_size,
                              hipStream_t stream) {
  const float* x    = (const float*)d_in[0];
  const float* wc   = (const float*)d_in[1];
  const float* kpe  = (const float*)d_in[2];
  const float* lnw  = (const float*)d_in[3];
  const float* lnb  = (const float*)d_in[4];
  const float* w1   = (const float*)d_in[5];
  const float* b1   = (const float*)d_in[6];
  const float* gam  = (const float*)d_in[7];
  const float* beta = (const float*)d_in[8];
  const float* w2   = (const float*)d_in[9];
  const float* b2   = (const float*)d_in[10];
  float* out = (float*)d_out;

  char* ws = (char*)d_ws;
  size_t o = 0;
  auto take = [&](size_t bytes)->char*{
    char* p = ws + o;
    o = (o + bytes + 511) & ~(size_t)511;
    return p;
  };
  // y (conv output) aliases d_out: fully consumed by k_gemm1g (fused LN) before
  // k_gemm2 writes the real output.
  float*          y     = out;
  float*          wfull = (float*)take((size_t)CDIM*2601*4);
  unsigned short* H     = (unsigned short*)take((size_t)NPIX*FDIM*2);
  unsigned short* w1T   = (unsigned short*)take((size_t)CDIM*FDIM*2);
  unsigned short* w2T   = (unsigned short*)take((size_t)CDIM*FDIM*2);
  unsigned short* W2s   = (unsigned short*)take((size_t)8*CDIM*FDIM*2);
  float*          grn   = (float*)take(8*FDIM*4);
  float*          S     = (float*)take(8*FDIM*4);
  float*          c2    = (float*)take(CDIM*4);
  if (o > ws_size) return;

  k_prep<<<679, 256, 0, stream>>>(wc, kpe, wfull, w1, w1T, w2, w2T, beta, b2, c2, grn);
  k_conv_mfma<<<1536, 256, 0, stream>>>(x, wfull, y, 0);
  k_conv_mfma<<<1536, 256, 0, stream>>>(x, wfull, y, 1536);
  k_gemm1g<<<NPIX/64, 256, 0, stream>>>(y, lnw, lnb, w1T, b1, H, grn);
  k_grn<<<8, 256, 0, stream>>>(grn, gam, S);
  k_scale<<<dim3(288, 8), 256, 0, stream>>>(w2T, S, W2s);
  k_gemm2<<<3*(NPIX/128), 256, 0, stream>>>(W2s, H, c2, x, out);
}

// Round 21
// 373.298 us; speedup vs baseline: 1.1680x; 1.1490x over previous
//
#include <hip/hip_runtime.h>

#define CDIM 384
#define FDIM 1536
#define KK 51
#define RAD 25
#define NPIX 32768     // B*H*W
#define HW 4096        // 64*64

#define CSTR 136       // shifted-copy stride (elements)
#define OSTR 68        // out accumulator row stride (f32 words)

typedef float  f32x4  __attribute__((ext_vector_type(4)));
typedef short  short8 __attribute__((ext_vector_type(8)));
typedef __bf16 bf16x8 __attribute__((ext_vector_type(8)));
typedef unsigned short us4 __attribute__((ext_vector_type(4)));

// per-axis peripheral index: coords {0,1,2,4,8,16,25}, signed list P=13
__device__ __constant__ int AXIS[51] = {
  0,
  1,1,1,1,1,1,1,1,1,
  2,2,2,2,2,2,2,2,
  3,3,3,3,
  4,4,
  5,
  6,
  7,
  8,8,
  9,9,9,9,
  10,10,10,10,10,10,10,10,
  11,11,11,11,11,11,11,11,11,
  12
};

__device__ __forceinline__ unsigned short bf16_rn(float x){
  union { float f; unsigned u; } v; v.f = x;
  unsigned r = v.u + 0x7FFFu + ((v.u >> 16) & 1u);
  return (unsigned short)(r >> 16);
}
__device__ __forceinline__ unsigned short f2bf(float x){
  __bf16 h = (__bf16)x;
  return __builtin_bit_cast(unsigned short, h);
}
__device__ __forceinline__ float bf2f(unsigned short h){
  union { unsigned u; float f; } v; v.u = ((unsigned)h) << 16; return v.f;
}
// fast GELU: v * sigmoid(2*sqrt(2/pi)*(v + 0.044715 v^3)); |err| vs exact erf <= ~1e-3
__device__ __forceinline__ float gelu_f(float v){
  float t = v*(0.7978845608f + 0.0356774081f*v*v);
  float sg = 1.f/(1.f + __expf(-2.f*t));
  return v * sg;
}

// ---------------- K-PREP: one launch for all small prep work.
// blocks [0,384): build wfull   [384,528): w1->w1T   [528,672): w2->w2T
// blocks [672,678): c2 (64 ch each)    [678]: zero grn
__global__ __launch_bounds__(256) void k_prep(const float* __restrict__ wc,
                                              const float* __restrict__ kpe,
                                              float* __restrict__ wfull,
                                              const float* __restrict__ w1,
                                              unsigned short* __restrict__ w1T,
                                              const float* __restrict__ w2,
                                              unsigned short* __restrict__ w2T,
                                              const float* __restrict__ beta,
                                              const float* __restrict__ b2,
                                              float* __restrict__ c2,
                                              float* __restrict__ grn){
  __shared__ float tile[64][65];
  __shared__ float red[256];
  int bid = blockIdx.x;
  int tid = threadIdx.x;
  if (bid < 384){
    int c = bid;
    const float* wcc = wc + c*169;
    float* wo = wfull + (size_t)c*2601;
    for (int idx = tid; idx < 2601; idx += 256){
      int i = idx / 51, j = idx - i*51;
      wo[idx] = wcc[AXIS[i]*13 + AXIS[j]] + kpe[idx];
    }
  } else if (bid < 672){  // transposes
    const float* src; unsigned short* dst; int R, C, t;
    if (bid < 528){ src = w1; dst = w1T; R = CDIM; C = FDIM; t = bid - 384; }
    else          { src = w2; dst = w2T; R = FDIM; C = CDIM; t = bid - 528; }
    int nct = C >> 6;
    int tc = t % nct, tr = t / nct;
    int r0 = tr*64, c0 = tc*64;
    int lane = tid & 63, q = tid >> 6;
    #pragma unroll
    for (int it = 0; it < 16; ++it){
      int r = it*4 + q;
      tile[r][lane] = src[(size_t)(r0 + r)*C + c0 + lane];
    }
    __syncthreads();
    #pragma unroll
    for (int it = 0; it < 16; ++it){
      int c = it*4 + q;
      dst[(size_t)(c0 + c)*R + r0 + lane] = f2bf(tile[lane][c]);
    }
  } else if (bid < 678){
    // c2[c] = b2[c] + sum_f beta[f]*w2[f,c]; lane = channel (coalesced rows)
    int lane = tid & 63, w = tid >> 6;
    int c = (bid - 672)*64 + lane;
    float s = 0.f;
    for (int f = w*384; f < (w + 1)*384; ++f)
      s += beta[f] * w2[(size_t)f*CDIM + c];
    red[w*64 + lane] = s;
    __syncthreads();
    if (tid < 64){
      float t = red[tid] + red[64 + tid] + red[128 + tid] + red[192 + tid];
      c2[c] = t + b2[c];
    }
  } else {
    for (int i = tid; i < 8*FDIM; i += 256) grn[i] = 0.f;
  }
}

// ---------------- K1: depthwise conv 51x51 via MFMA row-Toeplitz scatter,
// 4-row alignment-class batching + async-STAGE split. One block = one (b,c) image.
// (R12-measured best: ~160-163 us)
__global__ __launch_bounds__(256) void k_conv_mfma(const float* __restrict__ x,
                                                   const float* __restrict__ wfull,
                                                   float* __restrict__ y){
  __shared__ __align__(16) float outb[64*OSTR];              // 17408 B accumulator
  __shared__ __align__(16) unsigned short bufs[2][4][1088];  // 17408 B row copies
  int img = blockIdx.x;                 // b*384 + c
  int ch  = img % CDIM;
  const float* xim = x + (size_t)img*HW;
  const float* wch = wfull + (size_t)ch*2601;
  int tid = threadIdx.x;
  int lane = tid & 63, wid = tid >> 6;  // wid = q-tile
  int li = lane & 15, g = lane >> 4;
  int t0 = (lane & 31) << 2;            // us4 position within a copy
  int c0 = lane >> 5;                   // base copy index (it adds 2 per step)

  for (int i = tid; i < 1088; i += 256)
    *(f32x4*)&outb[i*4] = (f32x4){0.f,0.f,0.f,0.f};

  bf16x8 Bf[4][2];
  #pragma unroll
  for (int nt = 0; nt < 4; ++nt){
    int i = nt*16 + li;
    #pragma unroll
    for (int kt = 0; kt < 2; ++kt){
      union { bf16x8 v; unsigned short u[8]; } tmp;
      #pragma unroll
      for (int e = 0; e < 8; ++e){
        int j = kt*32 + g*8 + e;
        float v = (i < 51 && j < 51) ? wch[i*51 + j] : 0.f;
        tmp.u[e] = bf16_rn(v);
      }
      Bf[nt][kt] = tmp.v;
    }
  }

  {
    const float* xr = xim + (16*wid)*64;
    #pragma unroll
    for (int it = 0; it < 4; ++it){
      int c = c0 + 2*it;
      us4 o;
      #pragma unroll
      for (int e = 0; e < 4; ++e){
        int xi = t0 + e + c - 25;
        float v = (xi >= 0 && xi < 64) ? xr[xi] : 0.f;
        o[e] = bf16_rn(v);
      }
      *(us4*)&bufs[0][wid][c*CSTR + t0] = o;
    }
  }
  __syncthreads();

  #pragma unroll 1
  for (int ph = 0; ph < 16; ++ph){
    float pf[16];
    if (ph + 1 < 16){
      const float* xr = xim + (ph + 1 + 16*wid)*64;
      #pragma unroll
      for (int it = 0; it < 4; ++it){
        int c = c0 + 2*it;
        #pragma unroll
        for (int e = 0; e < 4; ++e){
          int xi = t0 + e + c - 25;
          int xc = min(max(xi, 0), 63);
          pf[it*4 + e] = xr[xc];
        }
      }
    }

    bf16x8 Af[4][2];
    #pragma unroll
    for (int s = 0; s < 4; ++s){
      const unsigned short* bb = &bufs[ph & 1][s][0];
      #pragma unroll
      for (int kt = 0; kt < 2; ++kt){
        int u0 = wid*16 + kt*32 + g*8 + li;
        int c  = li & 7;
        Af[s][kt] = *(const bf16x8*)&bb[c*CSTR + (u0 - c)];
      }
    }

    #pragma unroll
    for (int dd = 0; dd < 6; ++dd){
      int d = dd - 2;
      int pmax = ph + 25 + 16*d;
      if (pmax < 0 || pmax > 78) continue;
      f32x4 V = {0.f,0.f,0.f,0.f};
      #pragma unroll
      for (int s = 0; s < 4; ++s){
        int nt = s - d;
        if (nt < 0 || nt > 3) continue;
        V = __builtin_amdgcn_mfma_f32_16x16x32_bf16(Af[s][0], Bf[nt][0], V, 0, 0, 0);
        V = __builtin_amdgcn_mfma_f32_16x16x32_bf16(Af[s][1], Bf[nt][1], V, 0, 0, 0);
      }
      int p = pmax - li;
      if (p >= 0 && p < 64){
        float* oa = &outb[p*OSTR + wid*16 + g*4];
        f32x4 old = *(const f32x4*)oa;
        *(f32x4*)oa = old + V;
      }
    }

    if (ph + 1 < 16){
      unsigned short* dst = &bufs[(ph + 1) & 1][wid][0];
      #pragma unroll
      for (int it = 0; it < 4; ++it){
        int c = c0 + 2*it;
        us4 o;
        #pragma unroll
        for (int e = 0; e < 4; ++e){
          int xi = t0 + e + c - 25;
          float v = (xi >= 0 && xi < 64) ? pf[it*4 + e] : 0.f;
          o[e] = bf16_rn(v);
        }
        *(us4*)&dst[c*CSTR + t0] = o;
      }
    }
    __syncthreads();
  }

  float* yo = y + (size_t)img*HW;
  #pragma unroll
  for (int k = 0; k < 4; ++k){
    int pix = k*1024 + tid*4;
    int p = pix >> 6, q = pix & 63;
    *(f32x4*)(yo + pix) = *(const f32x4*)&outb[p*OSTR + q];
  }
}

// ---------------- K6: GEMM1 with FUSED LayerNorm (reads conv y f32 NCHW directly),
// persistent-A, single-barrier double-buffered B, fast GELU. (R12-measured best: ~124 us;
// tiled-128x128 and barrier-free-global-B variants measured 183/172 — occupancy stays
// ~22% regardless of LDS/barriers, so this is the best of the explored class.)
__global__ __launch_bounds__(256) void k_gemm1p(const float* __restrict__ y,      // conv out f32 NCHW
                                                const float* __restrict__ lnw,
                                                const float* __restrict__ lnb,
                                                const unsigned short* __restrict__ BT,  // w1T 1536 x 384
                                                const float* __restrict__ b1,
                                                unsigned short* __restrict__ H,         // M x 1536
                                                float* __restrict__ grn){               // 8 x 1536
  __shared__ __align__(16) unsigned short pan[64*392];     // 49.1 KB A panel
  __shared__ __align__(16) unsigned short bS[2][128*40];   // 2 x 10.25 KB B tiles
  __shared__ float sred[2][4][64];
  int m0 = blockIdx.x * 64;
  int img = m0 >> 12;
  int tid = threadIdx.x;
  int lane = tid & 63, wid = tid >> 6;
  int wr = wid >> 1, wc = wid & 1;     // wave tile: 32 pixels x 64 f
  int lm = lane & 15, g = lane >> 4;
  int sr = tid & 127, sc = tid >> 7;   // B staging coords

  // ---- fused LN: lane = pixel (64 per block), wave = channel quarter [96w, 96w+96)
  {
    int sp0 = m0 & 4095;
    const float* yb = y + (size_t)img*CDIM*HW + sp0 + lane;
    int cbase = wid*96;
    float v[96];
    float sum = 0.f, sq = 0.f;
    #pragma unroll
    for (int cc = 0; cc < 96; ++cc){
      float t = yb[(size_t)(cbase + cc)*HW];
      v[cc] = t; sum += t; sq += t*t;
    }
    sred[0][wid][lane] = sum; sred[1][wid][lane] = sq;
    __syncthreads();
    float ts = 0.f, tq = 0.f;
    #pragma unroll
    for (int u = 0; u < 4; ++u){ ts += sred[0][u][lane]; tq += sred[1][u][lane]; }
    float mu   = ts * (1.f/CDIM);
    float rstd = rsqrtf(tq * (1.f/CDIM) - mu*mu + 1e-6f);
    #pragma unroll
    for (int j = 0; j < 12; ++j){
      short8 o;
      #pragma unroll
      for (int e = 0; e < 8; ++e){
        int c = cbase + j*8 + e;
        float t = (v[j*8 + e] - mu) * rstd * lnw[c] + lnb[c];
        o[e] = (short)f2bf(t);
      }
      *(short8*)&pan[lane*392 + cbase + j*8] = o;   // row = pixel, contiguous c
    }
  }

  // prologue: step0 -> bS[0]; rn = step1; (pft,pk) = step2
  {
    const unsigned short* gb = BT + (size_t)sr*CDIM + sc*16;
    *(short8*)&bS[0][sr*40 + sc*16]     = *(const short8*)(gb);
    *(short8*)&bS[0][sr*40 + sc*16 + 8] = *(const short8*)(gb + 8);
  }
  short8 rn0, rn1;
  {
    const unsigned short* gb = BT + (size_t)sr*CDIM + 32 + sc*16;
    rn0 = *(const short8*)(gb);
    rn1 = *(const short8*)(gb + 8);
  }
  int pft = 0, pk = 64;
  int par = 0;

  #pragma unroll 1
  for (int ft = 0; ft < 12; ++ft){
    f32x4 acc[2][4];
    #pragma unroll
    for (int i = 0; i < 2; ++i)
      #pragma unroll
      for (int j = 0; j < 4; ++j) acc[i][j] = (f32x4){0.f,0.f,0.f,0.f};

    #pragma unroll 1
    for (int ks = 0; ks < 12; ++ks){
      int k0 = ks*32;
      __syncthreads();                 // also orders pan writes (first iter)
      if (!(ft == 11 && ks == 11)){
        *(short8*)&bS[par^1][sr*40 + sc*16]     = rn0;
        *(short8*)&bS[par^1][sr*40 + sc*16 + 8] = rn1;
      }
      if (!(ft == 11 && ks >= 10)){
        const unsigned short* gb = BT + (size_t)(pft*128 + sr)*CDIM + pk + sc*16;
        rn0 = *(const short8*)(gb);
        rn1 = *(const short8*)(gb + 8);
        pk += 32; if (pk == CDIM){ pk = 0; ++pft; }
      }
      bf16x8 aF[2], bF[4];
      #pragma unroll
      for (int fm = 0; fm < 2; ++fm) aF[fm] = *(const bf16x8*)&pan[(wr*32 + fm*16 + lm)*392 + k0 + g*8];
      #pragma unroll
      for (int fn = 0; fn < 4; ++fn) bF[fn] = *(const bf16x8*)&bS[par][(wc*64 + fn*16 + lm)*40 + g*8];
      #pragma unroll
      for (int fm = 0; fm < 2; ++fm)
        #pragma unroll
        for (int fn = 0; fn < 4; ++fn)
          acc[fm][fn] = __builtin_amdgcn_mfma_f32_16x16x32_bf16(aF[fm], bF[fn], acc[fm][fn], 0, 0, 0);
      par ^= 1;
    }

    int n0 = ft*128;
    float psum[4] = {0.f,0.f,0.f,0.f};
    #pragma unroll
    for (int fn = 0; fn < 4; ++fn){
      int n = n0 + wc*64 + fn*16 + lm;
      float bias = b1[n];
      #pragma unroll
      for (int fm = 0; fm < 2; ++fm){
        int mb = m0 + wr*32 + fm*16 + g*4;
        #pragma unroll
        for (int r = 0; r < 4; ++r){
          float v = gelu_f(acc[fm][fn][r] + bias);
          H[(size_t)(mb + r)*FDIM + n] = f2bf(v);
          psum[fn] += v*v;
        }
      }
    }
    #pragma unroll
    for (int fn = 0; fn < 4; ++fn){
      float v = psum[fn];
      v += __shfl_xor(v, 16);
      v += __shfl_xor(v, 32);
      if (g == 0){
        atomicAdd(&grn[img*FDIM + n0 + wc*64 + fn*16 + lm], v);
      }
    }
  }
}

// ---------------- K7: GRN finalize -> S[n,f] = 1 + gamma[f]*nx
__global__ __launch_bounds__(256) void k_grn(const float* __restrict__ grn,
                                             const float* __restrict__ gamma,
                                             float* __restrict__ S){
  int n = blockIdx.x;
  const float* g = grn + n*FDIM;
  __shared__ float red[256];
  float p = 0.f;
  for (int f = threadIdx.x; f < FDIM; f += 256) p += sqrtf(g[f]);
  red[threadIdx.x] = p;
  __syncthreads();
  for (int s = 128; s > 0; s >>= 1){
    if (threadIdx.x < s) red[threadIdx.x] += red[threadIdx.x + s];
    __syncthreads();
  }
  float mean = red[0] * (1.f/FDIM);
  float inv = 1.f/(mean + 1e-6f);
  for (int f = threadIdx.x; f < FDIM; f += 256){
    float nx = sqrtf(g[f]) * inv;
    S[n*FDIM + f] = 1.f + gamma[f]*nx;
  }
}

// ---------------- K-SCALE: W2s[img][c][f] = bf16( w2T[c][f] * S[img][f] )
__global__ __launch_bounds__(256) void k_scale(const unsigned short* __restrict__ w2T,
                                               const float* __restrict__ S,
                                               unsigned short* __restrict__ W2s){
  int img = blockIdx.y;
  size_t base = ((size_t)blockIdx.x*256 + threadIdx.x)*8;   // < 384*1536
  int f0 = (int)(base % FDIM);                              // 8 | FDIM -> f contiguous
  const float* Si = S + img*FDIM + f0;
  short8 wv = *(const short8*)(w2T + base);
  short8 o;
  #pragma unroll
  for (int e = 0; e < 8; ++e)
    o[e] = (short)f2bf(bf2f((unsigned short)wv[e]) * Si[e]);
  *(short8*)(W2s + (size_t)img*CDIM*FDIM + base) = o;
}

// ---------------- K9: GEMM2, single-barrier dbuf, pure-copy staging (S pre-folded).
__global__ __launch_bounds__(256) void k_gemm2(const unsigned short* __restrict__ W2s, // [8][384][1536]
                                               const unsigned short* __restrict__ H,   // M x 1536
                                               const float* __restrict__ c2,
                                               const float* __restrict__ xg,
                                               float* __restrict__ out){
  __shared__ __align__(16) unsigned short aS[2][128*40];
  __shared__ __align__(16) unsigned short bS[2][128*40];
  int bid = blockIdx.x;
  int x8 = bid & 7;            // XCD id
  int kk = bid >> 3;
  int bm = kk % 3;             // channel tile
  int bn = x8 + 8*(kk / 3);    // pixel tile
  int c0 = bm*128, p0 = bn*128;
  int img = p0 >> 12;
  const unsigned short* Wimg = W2s + (size_t)img*CDIM*FDIM;
  int tid = threadIdx.x;
  int lane = tid & 63, wid = tid >> 6;
  int wr = wid >> 1, wc = wid & 1;
  int lm = lane & 15, g = lane >> 4;
  int sr = tid & 127, sc = tid >> 7;
  f32x4 acc[4][4];
  #pragma unroll
  for (int i = 0; i < 4; ++i)
    #pragma unroll
    for (int j = 0; j < 4; ++j) acc[i][j] = (f32x4){0.f,0.f,0.f,0.f};

  // prologue: step0 directly to LDS; step1 to regs
  {
    const unsigned short* ga = Wimg + (size_t)(c0 + sr)*FDIM + sc*16;
    *(short8*)&aS[0][sr*40 + sc*16]     = *(const short8*)(ga);
    *(short8*)&aS[0][sr*40 + sc*16 + 8] = *(const short8*)(ga + 8);
    const unsigned short* gb = H + (size_t)(p0 + sr)*FDIM + sc*16;
    *(short8*)&bS[0][sr*40 + sc*16]     = *(const short8*)(gb);
    *(short8*)&bS[0][sr*40 + sc*16 + 8] = *(const short8*)(gb + 8);
  }
  short8 ra0, ra1, rh0, rh1;
  {
    const unsigned short* ga = Wimg + (size_t)(c0 + sr)*FDIM + 32 + sc*16;
    ra0 = *(const short8*)(ga); ra1 = *(const short8*)(ga + 8);
    const unsigned short* gb = H + (size_t)(p0 + sr)*FDIM + 32 + sc*16;
    rh0 = *(const short8*)(gb); rh1 = *(const short8*)(gb + 8);
  }
  int par = 0;

  #pragma unroll 1
  for (int ks = 0; ks < 48; ++ks){
    __syncthreads();
    if (ks + 1 < 48){
      *(short8*)&aS[par^1][sr*40 + sc*16]     = ra0;
      *(short8*)&aS[par^1][sr*40 + sc*16 + 8] = ra1;
      *(short8*)&bS[par^1][sr*40 + sc*16]     = rh0;
      *(short8*)&bS[par^1][sr*40 + sc*16 + 8] = rh1;
    }
    if (ks + 2 < 48){
      int nk = (ks + 2)*32;
      const unsigned short* ga = Wimg + (size_t)(c0 + sr)*FDIM + nk + sc*16;
      ra0 = *(const short8*)(ga); ra1 = *(const short8*)(ga + 8);
      const unsigned short* gb = H + (size_t)(p0 + sr)*FDIM + nk + sc*16;
      rh0 = *(const short8*)(gb); rh1 = *(const short8*)(gb + 8);
    }
    bf16x8 aF[4], bF[4];
    #pragma unroll
    for (int fm = 0; fm < 4; ++fm) aF[fm] = *(const bf16x8*)&aS[par][(wr*64 + fm*16 + lm)*40 + g*8];
    #pragma unroll
    for (int fn = 0; fn < 4; ++fn) bF[fn] = *(const bf16x8*)&bS[par][(wc*64 + fn*16 + lm)*40 + g*8];
    #pragma unroll
    for (int fm = 0; fm < 4; ++fm)
      #pragma unroll
      for (int fn = 0; fn < 4; ++fn)
        acc[fm][fn] = __builtin_amdgcn_mfma_f32_16x16x32_bf16(aF[fm], bF[fn], acc[fm][fn], 0, 0, 0);
    par ^= 1;
  }

  int sp0 = p0 & 4095;
  #pragma unroll
  for (int fn = 0; fn < 4; ++fn){
    int pixoff = sp0 + wc*64 + fn*16 + lm;
    #pragma unroll
    for (int fm = 0; fm < 4; ++fm){
      #pragma unroll
      for (int r = 0; r < 4; ++r){
        int c = c0 + wr*64 + fm*16 + g*4 + r;
        size_t addr = ((size_t)img*CDIM + c)*HW + pixoff;
        out[addr] = acc[fm][fn][r] + c2[c] + xg[addr];
      }
    }
  }
}

extern "C" void kernel_launch(void* const* d_in, const int* in_sizes, int n_in,
                              void* d_out, int out_size, void* d_ws, size_t ws_size,
                              hipStream_t stream) {
  const float* x    = (const float*)d_in[0];
  const float* wc   = (const float*)d_in[1];
  const float* kpe  = (const float*)d_in[2];
  const float* lnw  = (const float*)d_in[3];
  const float* lnb  = (const float*)d_in[4];
  const float* w1   = (const float*)d_in[5];
  const float* b1   = (const float*)d_in[6];
  const float* gam  = (const float*)d_in[7];
  const float* beta = (const float*)d_in[8];
  const float* w2   = (const float*)d_in[9];
  const float* b2   = (const float*)d_in[10];
  float* out = (float*)d_out;

  char* ws = (char*)d_ws;
  size_t o = 0;
  auto take = [&](size_t bytes)->char*{
    char* p = ws + o;
    o = (o + bytes + 511) & ~(size_t)511;
    return p;
  };
  // y (conv output) aliases d_out: fully consumed by k_gemm1p (fused LN) before
  // k_gemm2 writes the real output.
  float*          y     = out;
  float*          wfull = (float*)take((size_t)CDIM*2601*4);
  unsigned short* H     = (unsigned short*)take((size_t)NPIX*FDIM*2);
  unsigned short* w1T   = (unsigned short*)take((size_t)CDIM*FDIM*2);
  unsigned short* w2T   = (unsigned short*)take((size_t)CDIM*FDIM*2);
  unsigned short* W2s   = (unsigned short*)take((size_t)8*CDIM*FDIM*2);
  float*          grn   = (float*)take(8*FDIM*4);
  float*          S     = (float*)take(8*FDIM*4);
  float*          c2    = (float*)take(CDIM*4);
  if (o > ws_size) return;

  k_prep<<<679, 256, 0, stream>>>(wc, kpe, wfull, w1, w1T, w2, w2T, beta, b2, c2, grn);
  k_conv_mfma<<<3072, 256, 0, stream>>>(x, wfull, y);
  k_gemm1p<<<NPIX/64, 256, 0, stream>>>(y, lnw, lnb, w1T, b1, H, grn);
  k_grn<<<8, 256, 0, stream>>>(grn, gam, S);
  k_scale<<<dim3(288, 8), 256, 0, stream>>>(w2T, S, W2s);
  k_gemm2<<<3*(NPIX/128), 256, 0, stream>>>(W2s, H, c2, x, out);
}

// Round 22
// 367.197 us; speedup vs baseline: 1.1874x; 1.0166x over previous
//
#include <hip/hip_runtime.h>

#define CDIM 384
#define FDIM 1536
#define KK 51
#define RAD 25
#define NPIX 32768     // B*H*W
#define HW 4096        // 64*64

#define CSTR 136       // shifted-copy stride (elements)
#define OSTR 68        // out accumulator row stride (f32 words)

typedef float  f32x4  __attribute__((ext_vector_type(4)));
typedef short  short8 __attribute__((ext_vector_type(8)));
typedef __bf16 bf16x8 __attribute__((ext_vector_type(8)));
typedef unsigned short us4 __attribute__((ext_vector_type(4)));

// per-axis peripheral index: coords {0,1,2,4,8,16,25}, signed list P=13
__device__ __constant__ int AXIS[51] = {
  0,
  1,1,1,1,1,1,1,1,1,
  2,2,2,2,2,2,2,2,
  3,3,3,3,
  4,4,
  5,
  6,
  7,
  8,8,
  9,9,9,9,
  10,10,10,10,10,10,10,10,
  11,11,11,11,11,11,11,11,11,
  12
};

__device__ __forceinline__ unsigned short bf16_rn(float x){
  union { float f; unsigned u; } v; v.f = x;
  unsigned r = v.u + 0x7FFFu + ((v.u >> 16) & 1u);
  return (unsigned short)(r >> 16);
}
__device__ __forceinline__ unsigned short f2bf(float x){
  __bf16 h = (__bf16)x;
  return __builtin_bit_cast(unsigned short, h);
}
__device__ __forceinline__ float bf2f(unsigned short h){
  union { unsigned u; float f; } v; v.u = ((unsigned)h) << 16; return v.f;
}
// fast GELU: v * sigmoid(2*sqrt(2/pi)*(v + 0.044715 v^3)); |err| vs exact erf <= ~1e-3
__device__ __forceinline__ float gelu_f(float v){
  float t = v*(0.7978845608f + 0.0356774081f*v*v);
  float sg = 1.f/(1.f + __expf(-2.f*t));
  return v * sg;
}

// ---------------- K-PREP: one launch for all small prep work.
// blocks [0,384): build wfull   [384,528): w1->w1T   [528,672): w2->w2T
// blocks [672,678): c2 (64 ch each)    [678]: zero grn
__global__ __launch_bounds__(256) void k_prep(const float* __restrict__ wc,
                                              const float* __restrict__ kpe,
                                              float* __restrict__ wfull,
                                              const float* __restrict__ w1,
                                              unsigned short* __restrict__ w1T,
                                              const float* __restrict__ w2,
                                              unsigned short* __restrict__ w2T,
                                              const float* __restrict__ beta,
                                              const float* __restrict__ b2,
                                              float* __restrict__ c2,
                                              float* __restrict__ grn){
  __shared__ float tile[64][65];
  __shared__ float red[256];
  int bid = blockIdx.x;
  int tid = threadIdx.x;
  if (bid < 384){
    int c = bid;
    const float* wcc = wc + c*169;
    float* wo = wfull + (size_t)c*2601;
    for (int idx = tid; idx < 2601; idx += 256){
      int i = idx / 51, j = idx - i*51;
      wo[idx] = wcc[AXIS[i]*13 + AXIS[j]] + kpe[idx];
    }
  } else if (bid < 672){  // transposes
    const float* src; unsigned short* dst; int R, C, t;
    if (bid < 528){ src = w1; dst = w1T; R = CDIM; C = FDIM; t = bid - 384; }
    else          { src = w2; dst = w2T; R = FDIM; C = CDIM; t = bid - 528; }
    int nct = C >> 6;
    int tc = t % nct, tr = t / nct;
    int r0 = tr*64, c0 = tc*64;
    int lane = tid & 63, q = tid >> 6;
    #pragma unroll
    for (int it = 0; it < 16; ++it){
      int r = it*4 + q;
      tile[r][lane] = src[(size_t)(r0 + r)*C + c0 + lane];
    }
    __syncthreads();
    #pragma unroll
    for (int it = 0; it < 16; ++it){
      int c = it*4 + q;
      dst[(size_t)(c0 + c)*R + r0 + lane] = f2bf(tile[lane][c]);
    }
  } else if (bid < 678){
    // c2[c] = b2[c] + sum_f beta[f]*w2[f,c]; lane = channel (coalesced rows)
    int lane = tid & 63, w = tid >> 6;
    int c = (bid - 672)*64 + lane;
    float s = 0.f;
    for (int f = w*384; f < (w + 1)*384; ++f)
      s += beta[f] * w2[(size_t)f*CDIM + c];
    red[w*64 + lane] = s;
    __syncthreads();
    if (tid < 64){
      float t = red[tid] + red[64 + tid] + red[128 + tid] + red[192 + tid];
      c2[c] = t + b2[c];
    }
  } else {
    for (int i = tid; i < 8*FDIM; i += 256) grn[i] = 0.f;
  }
}

// ---------------- K1: depthwise conv 51x51 via MFMA row-Toeplitz scatter,
// 4-row alignment-class batching + async-STAGE split. One block = one (b,c) image.
// (R12/R21-measured best: ~160-163 us)
__global__ __launch_bounds__(256) void k_conv_mfma(const float* __restrict__ x,
                                                   const float* __restrict__ wfull,
                                                   float* __restrict__ y){
  __shared__ __align__(16) float outb[64*OSTR];              // 17408 B accumulator
  __shared__ __align__(16) unsigned short bufs[2][4][1088];  // 17408 B row copies
  int img = blockIdx.x;                 // b*384 + c
  int ch  = img % CDIM;
  const float* xim = x + (size_t)img*HW;
  const float* wch = wfull + (size_t)ch*2601;
  int tid = threadIdx.x;
  int lane = tid & 63, wid = tid >> 6;  // wid = q-tile
  int li = lane & 15, g = lane >> 4;
  int t0 = (lane & 31) << 2;            // us4 position within a copy
  int c0 = lane >> 5;                   // base copy index (it adds 2 per step)

  for (int i = tid; i < 1088; i += 256)
    *(f32x4*)&outb[i*4] = (f32x4){0.f,0.f,0.f,0.f};

  bf16x8 Bf[4][2];
  #pragma unroll
  for (int nt = 0; nt < 4; ++nt){
    int i = nt*16 + li;
    #pragma unroll
    for (int kt = 0; kt < 2; ++kt){
      union { bf16x8 v; unsigned short u[8]; } tmp;
      #pragma unroll
      for (int e = 0; e < 8; ++e){
        int j = kt*32 + g*8 + e;
        float v = (i < 51 && j < 51) ? wch[i*51 + j] : 0.f;
        tmp.u[e] = bf16_rn(v);
      }
      Bf[nt][kt] = tmp.v;
    }
  }

  {
    const float* xr = xim + (16*wid)*64;
    #pragma unroll
    for (int it = 0; it < 4; ++it){
      int c = c0 + 2*it;
      us4 o;
      #pragma unroll
      for (int e = 0; e < 4; ++e){
        int xi = t0 + e + c - 25;
        float v = (xi >= 0 && xi < 64) ? xr[xi] : 0.f;
        o[e] = bf16_rn(v);
      }
      *(us4*)&bufs[0][wid][c*CSTR + t0] = o;
    }
  }
  __syncthreads();

  #pragma unroll 1
  for (int ph = 0; ph < 16; ++ph){
    float pf[16];
    if (ph + 1 < 16){
      const float* xr = xim + (ph + 1 + 16*wid)*64;
      #pragma unroll
      for (int it = 0; it < 4; ++it){
        int c = c0 + 2*it;
        #pragma unroll
        for (int e = 0; e < 4; ++e){
          int xi = t0 + e + c - 25;
          int xc = min(max(xi, 0), 63);
          pf[it*4 + e] = xr[xc];
        }
      }
    }

    bf16x8 Af[4][2];
    #pragma unroll
    for (int s = 0; s < 4; ++s){
      const unsigned short* bb = &bufs[ph & 1][s][0];
      #pragma unroll
      for (int kt = 0; kt < 2; ++kt){
        int u0 = wid*16 + kt*32 + g*8 + li;
        int c  = li & 7;
        Af[s][kt] = *(const bf16x8*)&bb[c*CSTR + (u0 - c)];
      }
    }

    #pragma unroll
    for (int dd = 0; dd < 6; ++dd){
      int d = dd - 2;
      int pmax = ph + 25 + 16*d;
      if (pmax < 0 || pmax > 78) continue;
      f32x4 V = {0.f,0.f,0.f,0.f};
      #pragma unroll
      for (int s = 0; s < 4; ++s){
        int nt = s - d;
        if (nt < 0 || nt > 3) continue;
        V = __builtin_amdgcn_mfma_f32_16x16x32_bf16(Af[s][0], Bf[nt][0], V, 0, 0, 0);
        V = __builtin_amdgcn_mfma_f32_16x16x32_bf16(Af[s][1], Bf[nt][1], V, 0, 0, 0);
      }
      int p = pmax - li;
      if (p >= 0 && p < 64){
        float* oa = &outb[p*OSTR + wid*16 + g*4];
        f32x4 old = *(const f32x4*)oa;
        *(f32x4*)oa = old + V;
      }
    }

    if (ph + 1 < 16){
      unsigned short* dst = &bufs[(ph + 1) & 1][wid][0];
      #pragma unroll
      for (int it = 0; it < 4; ++it){
        int c = c0 + 2*it;
        us4 o;
        #pragma unroll
        for (int e = 0; e < 4; ++e){
          int xi = t0 + e + c - 25;
          float v = (xi >= 0 && xi < 64) ? pf[it*4 + e] : 0.f;
          o[e] = bf16_rn(v);
        }
        *(us4*)&dst[c*CSTR + t0] = o;
      }
    }
    __syncthreads();
  }

  float* yo = y + (size_t)img*HW;
  #pragma unroll
  for (int k = 0; k < 4; ++k){
    int pix = k*1024 + tid*4;
    int p = pix >> 6, q = pix & 63;
    *(f32x4*)(yo + pix) = *(const f32x4*)&outb[p*OSTR + q];
  }
}

// ---------------- K6: GEMM1 with FUSED LayerNorm, 512 threads / 8 waves:
// same 64px x 1536f block and LDS tiles as the 124us 4-wave version, but the
// 128-f tile is split 4 ways (wave = 32px x 32f, 4 MFMA/k-step). Waves/CU
// 8 -> 16 (2 -> 4 per SIMD) at unchanged 2 blocks/CU: attacks the measured
// invariant 22% occupancy (latency chains were hidden by only 2 waves/SIMD).
__global__ __launch_bounds__(512) void k_gemm1p(const float* __restrict__ y,      // conv out f32 NCHW
                                                const float* __restrict__ lnw,
                                                const float* __restrict__ lnb,
                                                const unsigned short* __restrict__ BT,  // w1T 1536 x 384
                                                const float* __restrict__ b1,
                                                unsigned short* __restrict__ H,         // M x 1536
                                                float* __restrict__ grn){               // 8 x 1536
  __shared__ __align__(16) unsigned short pan[64*392];     // 49.1 KB A panel
  __shared__ __align__(16) unsigned short bS[2][128*40];   // 2 x 10.25 KB B tiles
  __shared__ float sred[2][8][64];
  int m0 = blockIdx.x * 64;
  int img = m0 >> 12;
  int tid = threadIdx.x;
  int lane = tid & 63, wid = tid >> 6;   // wid in [0,8)
  int wr = wid >> 2, wc = wid & 3;       // wave tile: 32 pixels x 32 f
  int lm = lane & 15, g = lane >> 4;
  int sr = tid & 127, sc = tid >> 7;     // B staging: sc in [0,4), one short8 each

  // ---- fused LN: lane = pixel (64 per block), wave = channel eighth [48w, 48w+48)
  {
    int sp0 = m0 & 4095;
    const float* yb = y + (size_t)img*CDIM*HW + sp0 + lane;
    int cbase = wid*48;
    float v[48];
    float sum = 0.f, sq = 0.f;
    #pragma unroll
    for (int cc = 0; cc < 48; ++cc){
      float t = yb[(size_t)(cbase + cc)*HW];
      v[cc] = t; sum += t; sq += t*t;
    }
    sred[0][wid][lane] = sum; sred[1][wid][lane] = sq;
    __syncthreads();
    float ts = 0.f, tq = 0.f;
    #pragma unroll
    for (int u = 0; u < 8; ++u){ ts += sred[0][u][lane]; tq += sred[1][u][lane]; }
    float mu   = ts * (1.f/CDIM);
    float rstd = rsqrtf(tq * (1.f/CDIM) - mu*mu + 1e-6f);
    #pragma unroll
    for (int j = 0; j < 6; ++j){
      short8 o;
      #pragma unroll
      for (int e = 0; e < 8; ++e){
        int c = cbase + j*8 + e;
        float t = (v[j*8 + e] - mu) * rstd * lnw[c] + lnb[c];
        o[e] = (short)f2bf(t);
      }
      *(short8*)&pan[lane*392 + cbase + j*8] = o;   // row = pixel, contiguous c
    }
  }

  // prologue: step0 -> bS[0]; rn = step1; (pft,pk) = step2
  {
    const unsigned short* gb = BT + (size_t)sr*CDIM + sc*8;
    *(short8*)&bS[0][sr*40 + sc*8] = *(const short8*)(gb);
  }
  short8 rn0;
  {
    const unsigned short* gb = BT + (size_t)sr*CDIM + 32 + sc*8;
    rn0 = *(const short8*)(gb);
  }
  int pft = 0, pk = 64;
  int par = 0;

  #pragma unroll 1
  for (int ft = 0; ft < 12; ++ft){
    f32x4 acc[2][2];
    #pragma unroll
    for (int i = 0; i < 2; ++i)
      #pragma unroll
      for (int j = 0; j < 2; ++j) acc[i][j] = (f32x4){0.f,0.f,0.f,0.f};

    #pragma unroll 1
    for (int ks = 0; ks < 12; ++ks){
      int k0 = ks*32;
      __syncthreads();                 // also orders pan writes (first iter)
      if (!(ft == 11 && ks == 11)){
        *(short8*)&bS[par^1][sr*40 + sc*8] = rn0;
      }
      if (!(ft == 11 && ks >= 10)){
        const unsigned short* gb = BT + (size_t)(pft*128 + sr)*CDIM + pk + sc*8;
        rn0 = *(const short8*)(gb);
        pk += 32; if (pk == CDIM){ pk = 0; ++pft; }
      }
      bf16x8 aF[2], bF[2];
      #pragma unroll
      for (int fm = 0; fm < 2; ++fm) aF[fm] = *(const bf16x8*)&pan[(wr*32 + fm*16 + lm)*392 + k0 + g*8];
      #pragma unroll
      for (int fn = 0; fn < 2; ++fn) bF[fn] = *(const bf16x8*)&bS[par][(wc*32 + fn*16 + lm)*40 + g*8];
      #pragma unroll
      for (int fm = 0; fm < 2; ++fm)
        #pragma unroll
        for (int fn = 0; fn < 2; ++fn)
          acc[fm][fn] = __builtin_amdgcn_mfma_f32_16x16x32_bf16(aF[fm], bF[fn], acc[fm][fn], 0, 0, 0);
      par ^= 1;
    }

    int n0 = ft*128;
    float psum[2] = {0.f,0.f};
    #pragma unroll
    for (int fn = 0; fn < 2; ++fn){
      int n = n0 + wc*32 + fn*16 + lm;
      float bias = b1[n];
      #pragma unroll
      for (int fm = 0; fm < 2; ++fm){
        int mb = m0 + wr*32 + fm*16 + g*4;
        #pragma unroll
        for (int r = 0; r < 4; ++r){
          float v = gelu_f(acc[fm][fn][r] + bias);
          H[(size_t)(mb + r)*FDIM + n] = f2bf(v);
          psum[fn] += v*v;
        }
      }
    }
    #pragma unroll
    for (int fn = 0; fn < 2; ++fn){
      float v = psum[fn];
      v += __shfl_xor(v, 16);
      v += __shfl_xor(v, 32);
      if (g == 0){
        atomicAdd(&grn[img*FDIM + n0 + wc*32 + fn*16 + lm], v);
      }
    }
  }
}

// ---------------- K7: GRN finalize -> S[n,f] = 1 + gamma[f]*nx
__global__ __launch_bounds__(256) void k_grn(const float* __restrict__ grn,
                                             const float* __restrict__ gamma,
                                             float* __restrict__ S){
  int n = blockIdx.x;
  const float* g = grn + n*FDIM;
  __shared__ float red[256];
  float p = 0.f;
  for (int f = threadIdx.x; f < FDIM; f += 256) p += sqrtf(g[f]);
  red[threadIdx.x] = p;
  __syncthreads();
  for (int s = 128; s > 0; s >>= 1){
    if (threadIdx.x < s) red[threadIdx.x] += red[threadIdx.x + s];
    __syncthreads();
  }
  float mean = red[0] * (1.f/FDIM);
  float inv = 1.f/(mean + 1e-6f);
  for (int f = threadIdx.x; f < FDIM; f += 256){
    float nx = sqrtf(g[f]) * inv;
    S[n*FDIM + f] = 1.f + gamma[f]*nx;
  }
}

// ---------------- K-SCALE: W2s[img][c][f] = bf16( w2T[c][f] * S[img][f] )
__global__ __launch_bounds__(256) void k_scale(const unsigned short* __restrict__ w2T,
                                               const float* __restrict__ S,
                                               unsigned short* __restrict__ W2s){
  int img = blockIdx.y;
  size_t base = ((size_t)blockIdx.x*256 + threadIdx.x)*8;   // < 384*1536
  int f0 = (int)(base % FDIM);                              // 8 | FDIM -> f contiguous
  const float* Si = S + img*FDIM + f0;
  short8 wv = *(const short8*)(w2T + base);
  short8 o;
  #pragma unroll
  for (int e = 0; e < 8; ++e)
    o[e] = (short)f2bf(bf2f((unsigned short)wv[e]) * Si[e]);
  *(short8*)(W2s + (size_t)img*CDIM*FDIM + base) = o;
}

// ---------------- K9: GEMM2, single-barrier dbuf, pure-copy staging (S pre-folded).
__global__ __launch_bounds__(256) void k_gemm2(const unsigned short* __restrict__ W2s, // [8][384][1536]
                                               const unsigned short* __restrict__ H,   // M x 1536
                                               const float* __restrict__ c2,
                                               const float* __restrict__ xg,
                                               float* __restrict__ out){
  __shared__ __align__(16) unsigned short aS[2][128*40];
  __shared__ __align__(16) unsigned short bS[2][128*40];
  int bid = blockIdx.x;
  int x8 = bid & 7;            // XCD id
  int kk = bid >> 3;
  int bm = kk % 3;             // channel tile
  int bn = x8 + 8*(kk / 3);    // pixel tile
  int c0 = bm*128, p0 = bn*128;
  int img = p0 >> 12;
  const unsigned short* Wimg = W2s + (size_t)img*CDIM*FDIM;
  int tid = threadIdx.x;
  int lane = tid & 63, wid = tid >> 6;
  int wr = wid >> 1, wc = wid & 1;
  int lm = lane & 15, g = lane >> 4;
  int sr = tid & 127, sc = tid >> 7;
  f32x4 acc[4][4];
  #pragma unroll
  for (int i = 0; i < 4; ++i)
    #pragma unroll
    for (int j = 0; j < 4; ++j) acc[i][j] = (f32x4){0.f,0.f,0.f,0.f};

  // prologue: step0 directly to LDS; step1 to regs
  {
    const unsigned short* ga = Wimg + (size_t)(c0 + sr)*FDIM + sc*16;
    *(short8*)&aS[0][sr*40 + sc*16]     = *(const short8*)(ga);
    *(short8*)&aS[0][sr*40 + sc*16 + 8] = *(const short8*)(ga + 8);
    const unsigned short* gb = H + (size_t)(p0 + sr)*FDIM + sc*16;
    *(short8*)&bS[0][sr*40 + sc*16]     = *(const short8*)(gb);
    *(short8*)&bS[0][sr*40 + sc*16 + 8] = *(const short8*)(gb + 8);
  }
  short8 ra0, ra1, rh0, rh1;
  {
    const unsigned short* ga = Wimg + (size_t)(c0 + sr)*FDIM + 32 + sc*16;
    ra0 = *(const short8*)(ga); ra1 = *(const short8*)(ga + 8);
    const unsigned short* gb = H + (size_t)(p0 + sr)*FDIM + 32 + sc*16;
    rh0 = *(const short8*)(gb); rh1 = *(const short8*)(gb + 8);
  }
  int par = 0;

  #pragma unroll 1
  for (int ks = 0; ks < 48; ++ks){
    __syncthreads();
    if (ks + 1 < 48){
      *(short8*)&aS[par^1][sr*40 + sc*16]     = ra0;
      *(short8*)&aS[par^1][sr*40 + sc*16 + 8] = ra1;
      *(short8*)&bS[par^1][sr*40 + sc*16]     = rh0;
      *(short8*)&bS[par^1][sr*40 + sc*16 + 8] = rh1;
    }
    if (ks + 2 < 48){
      int nk = (ks + 2)*32;
      const unsigned short* ga = Wimg + (size_t)(c0 + sr)*FDIM + nk + sc*16;
      ra0 = *(const short8*)(ga); ra1 = *(const short8*)(ga + 8);
      const unsigned short* gb = H + (size_t)(p0 + sr)*FDIM + nk + sc*16;
      rh0 = *(const short8*)(gb); rh1 = *(const short8*)(gb + 8);
    }
    bf16x8 aF[4], bF[4];
    #pragma unroll
    for (int fm = 0; fm < 4; ++fm) aF[fm] = *(const bf16x8*)&aS[par][(wr*64 + fm*16 + lm)*40 + g*8];
    #pragma unroll
    for (int fn = 0; fn < 4; ++fn) bF[fn] = *(const bf16x8*)&bS[par][(wc*64 + fn*16 + lm)*40 + g*8];
    #pragma unroll
    for (int fm = 0; fm < 4; ++fm)
      #pragma unroll
      for (int fn = 0; fn < 4; ++fn)
        acc[fm][fn] = __builtin_amdgcn_mfma_f32_16x16x32_bf16(aF[fm], bF[fn], acc[fm][fn], 0, 0, 0);
    par ^= 1;
  }

  int sp0 = p0 & 4095;
  #pragma unroll
  for (int fn = 0; fn < 4; ++fn){
    int pixoff = sp0 + wc*64 + fn*16 + lm;
    #pragma unroll
    for (int fm = 0; fm < 4; ++fm){
      #pragma unroll
      for (int r = 0; r < 4; ++r){
        int c = c0 + wr*64 + fm*16 + g*4 + r;
        size_t addr = ((size_t)img*CDIM + c)*HW + pixoff;
        out[addr] = acc[fm][fn][r] + c2[c] + xg[addr];
      }
    }
  }
}

extern "C" void kernel_launch(void* const* d_in, const int* in_sizes, int n_in,
                              void* d_out, int out_size, void* d_ws, size_t ws_size,
                              hipStream_t stream) {
  const float* x    = (const float*)d_in[0];
  const float* wc   = (const float*)d_in[1];
  const float* kpe  = (const float*)d_in[2];
  const float* lnw  = (const float*)d_in[3];
  const float* lnb  = (const float*)d_in[4];
  const float* w1   = (const float*)d_in[5];
  const float* b1   = (const float*)d_in[6];
  const float* gam  = (const float*)d_in[7];
  const float* beta = (const float*)d_in[8];
  const float* w2   = (const float*)d_in[9];
  const float* b2   = (const float*)d_in[10];
  float* out = (float*)d_out;

  char* ws = (char*)d_ws;
  size_t o = 0;
  auto take = [&](size_t bytes)->char*{
    char* p = ws + o;
    o = (o + bytes + 511) & ~(size_t)511;
    return p;
  };
  // y (conv output) aliases d_out: fully consumed by k_gemm1p (fused LN) before
  // k_gemm2 writes the real output.
  float*          y     = out;
  float*          wfull = (float*)take((size_t)CDIM*2601*4);
  unsigned short* H     = (unsigned short*)take((size_t)NPIX*FDIM*2);
  unsigned short* w1T   = (unsigned short*)take((size_t)CDIM*FDIM*2);
  unsigned short* w2T   = (unsigned short*)take((size_t)CDIM*FDIM*2);
  unsigned short* W2s   = (unsigned short*)take((size_t)8*CDIM*FDIM*2);
  float*          grn   = (float*)take(8*FDIM*4);
  float*          S     = (float*)take(8*FDIM*4);
  float*          c2    = (float*)take(CDIM*4);
  if (o > ws_size) return;

  k_prep<<<679, 256, 0, stream>>>(wc, kpe, wfull, w1, w1T, w2, w2T, beta, b2, c2, grn);
  k_conv_mfma<<<3072, 256, 0, stream>>>(x, wfull, y);
  k_gemm1p<<<NPIX/64, 512, 0, stream>>>(y, lnw, lnb, w1T, b1, H, grn);
  k_grn<<<8, 256, 0, stream>>>(grn, gam, S);
  k_scale<<<dim3(288, 8), 256, 0, stream>>>(w2T, S, W2s);
  k_gemm2<<<3*(NPIX/128), 256, 0, stream>>>(W2s, H, c2, x, out);
}